// Round 13
// baseline (329.575 us; speedup 1.0000x reference)
//
#include <hip/hip_runtime.h>
#include <hip/hip_bf16.h>

// Swin block, B=32 H=W=56 C=128, ws=7 (N=49), nh=4 (hd=32), shift=3, hid=512.
// fp32 in/out. All GEMMs AND attention (QK^T, AV) via mfma_f32_16x16x32_bf16.
// roll(-3) gather == roll(+3) scatter target -> fully fused windows.
// R18: register-resident attention. Discovery: VGPR cap = 256/launch_bounds
//     min-waves (measured 32/40/64 at (1024,8)/(512,6)/(512,4)) -> all prior
//     rounds ran at a 64-reg cap and spilled when exceeded (R8/R11/R15).
//     LDS pins us at 2 blocks/CU anyway, so (512,2) [cap 128] is free.
//     With the headroom: each wave computes its own head's K and V into
//     REGISTER A-fragments via the proven quad-group exchanges (K = Q's
//     select-by-tq pattern; V computed D[m][f] = P's select-by-mt pattern).
//     Kl/vTl LDS deleted; QKV+QK^T+softmax+AV is one barrier-free per-wave
//     stretch; o -> region B. LN2 via cross-wave partials (pt, fp32 exact)
//     + bf16 x2 tile (one extra rounding; NOT R17's failed matmul fold).
//     Barriers 9 -> 8. LDS 17408 + 34816 + 4608 = 56832 B.

#define NWIN 2048

typedef short short8  __attribute__((ext_vector_type(8)));
typedef short short4v __attribute__((ext_vector_type(4)));
typedef float f32x4   __attribute__((ext_vector_type(4)));

union Frag { int i[4]; unsigned u[4]; short8 s; };

#define QKVW_OFF  0        // 384*128 bf16
#define PROJW_OFF 49152    // 128*128
#define W1_OFF    65536    // 512*128
#define W2_OFF    131072   // 128*512
#define BIAS_BYTE_OFF 393216  // biasT[4][64][64] fp32 (padded, 0 outside 49x49)

__device__ __forceinline__ short f2bs(float v) {
  __hip_bfloat16 h = __float2bfloat16(v);
  union { __hip_bfloat16 h; short s; } u; u.h = h; return u.s;
}
__device__ __forceinline__ float bs2f(__hip_bfloat16 h) { return __bfloat162float(h); }
__device__ __forceinline__ float gelu_f(float v) {
  float u = v * (0.7978845608028654f + 0.03567740814f * v * v);
  return v * __builtin_amdgcn_rcpf(1.f + __expf(-2.f * u));
}

// ---------------- pre-pass: weights -> bf16, padded bias^T gather ----------------
__global__ __launch_bounds__(256) void conv_kernel(
    const float* __restrict__ qkvw, const float* __restrict__ projw,
    const float* __restrict__ w1,   const float* __restrict__ w2,
    const float* __restrict__ tab,  const int* __restrict__ ridx,
    __hip_bfloat16* __restrict__ wsb, float* __restrict__ biasT)
{
  int idx = blockIdx.x * 256 + threadIdx.x;
  if (idx < 49152)       wsb[QKVW_OFF + idx]          = __float2bfloat16(qkvw[idx]);
  else if (idx < 65536)  wsb[PROJW_OFF + idx - 49152] = __float2bfloat16(projw[idx - 49152]);
  else if (idx < 131072) wsb[W1_OFF + idx - 65536]    = __float2bfloat16(w1[idx - 65536]);
  else if (idx < 196608) wsb[W2_OFF + idx - 131072]   = __float2bfloat16(w2[idx - 131072]);
  else if (idx < 212992) {
    int i = idx - 196608;
    int h = i >> 12, m = (i >> 6) & 63, n = i & 63;   // biasT[h][m=key][n=query]
    biasT[i] = (m < 49 && n < 49) ? tab[ridx[n*49 + m]*4 + h] : 0.f;
  }
}

// ------- fused: LN1 + window attn + proj + shortcut + LN2 + MLP + residual -------
__global__ __launch_bounds__(512, 2) void fused_kernel(
    const float* __restrict__ x,
    const float* __restrict__ n1g, const float* __restrict__ n1b,
    const __hip_bfloat16* __restrict__ qkvwb, const float* __restrict__ qkvb,
    const float* __restrict__ biasT,
    const __hip_bfloat16* __restrict__ projwb, const float* __restrict__ projb,
    const float* __restrict__ n2g, const float* __restrict__ n2b,
    const __hip_bfloat16* __restrict__ w1b, const float* __restrict__ b1,
    const __hip_bfloat16* __restrict__ w2b, const float* __restrict__ b2,
    float* __restrict__ out)
{
  __shared__ alignas(16) __hip_bfloat16 hbuf[64][136];   // 17408 B: h / ln2
  __shared__ alignas(16) char shmem[34816];              // oB+x2b | hbA+hbB
  __shared__ float pt[64][9][2];                         // LN2 partials (4608 B)
  __hip_bfloat16* const oB  = (__hip_bfloat16*)shmem;            // [64][136] o tile
  __hip_bfloat16* const x2b = (__hip_bfloat16*)(shmem + 17408);  // [64][136] x2 bf16
  __hip_bfloat16* const hbA = (__hip_bfloat16*)shmem;            // MLP hidden A
  __hip_bfloat16* const hbB = (__hip_bfloat16*)(shmem + 17408);  // MLP hidden B

  const int tid = threadIdx.x, wave = tid >> 6, lane = tid & 63;
  const int l15 = lane & 15, quad = lane >> 4;
  const int h = wave >> 1, half = wave & 1;
  const int b = blockIdx.x >> 6, wi = (blockIdx.x >> 3) & 7, wj = blockIdx.x & 7;

  // ---- phase 1: LN1 over source rows (roll -3) -> hbuf bf16 ----
  {
    float g0 = n1g[lane], g1 = n1g[lane+64], e0 = n1b[lane], e1 = n1b[lane+64];
    float va[7], vb[7];
    #pragma unroll
    for (int i = 0; i < 7; ++i) {
      int n = wave + i*8;
      va[i] = 0.f; vb[i] = 0.f;
      if (n < 49) {
        int r = n / 7, c = n - r * 7;
        int si = wi*7 + r + 3; if (si >= 56) si -= 56;
        int sj = wj*7 + c + 3; if (sj >= 56) sj -= 56;
        const float* xr = x + (b*3136 + si*56 + sj) * 128;
        va[i] = xr[lane]; vb[i] = xr[lane + 64];
      }
    }
    #pragma unroll
    for (int i = 0; i < 7; ++i) {
      int n = wave + i*8;
      if (n < 49) {
        float s = va[i] + vb[i], sq = va[i]*va[i] + vb[i]*vb[i];
        #pragma unroll
        for (int off = 32; off > 0; off >>= 1) {
          s  += __shfl_xor(s,  off);
          sq += __shfl_xor(sq, off);
        }
        float mean = s * 0.0078125f;
        float var  = sq * 0.0078125f - mean*mean;
        float rstd = rsqrtf(var + 1e-5f);
        hbuf[n][lane]    = __float2bfloat16((va[i]-mean)*rstd*g0 + e0);
        hbuf[n][lane+64] = __float2bfloat16((vb[i]-mean)*rstd*g1 + e1);
      }
    }
  }
  __syncthreads();   // B1: h ready

  // ======== barrier-free per-wave stretch: QKV + attention, all in regs ========
  Frag qfr[2], kfr[4], vfr[2][2];

  // ---- Q (own n-half) -> B-fragments ----
  {
    f32x4 qacc[2][2] = {};   // [tq][nt]  D[f][m]
    #pragma unroll
    for (int ks = 0; ks < 4; ++ks) {
      short8 hfq[2];
      #pragma unroll
      for (int nt = 0; nt < 2; ++nt)
        hfq[nt] = *(const short8*)(&hbuf[(half*2 + nt)*16 + l15][ks*32 + quad*8]);
      #pragma unroll
      for (int tq = 0; tq < 2; ++tq) {
        short8 wf = *(const short8*)(qkvwb + (h*32 + tq*16 + l15)*128 + ks*32 + quad*8);
        #pragma unroll
        for (int nt = 0; nt < 2; ++nt)
          qacc[tq][nt] = __builtin_amdgcn_mfma_f32_16x16x32_bf16(wf, hfq[nt], qacc[tq][nt], 0, 0, 0);
      }
    }
    const float qs = 0.17677669529663687f;
    unsigned pkq[2][2][2];
    #pragma unroll
    for (int tq = 0; tq < 2; ++tq) {
      float bb[4];
      #pragma unroll
      for (int r = 0; r < 4; ++r) bb[r] = qkvb[h*32 + tq*16 + quad*4 + r];
      #pragma unroll
      for (int nt = 0; nt < 2; ++nt)
        #pragma unroll
        for (int i = 0; i < 2; ++i) {
          unsigned lo = (unsigned short)f2bs((qacc[tq][nt][2*i]   + bb[2*i])   * qs);
          unsigned hi = (unsigned short)f2bs((qacc[tq][nt][2*i+1] + bb[2*i+1]) * qs);
          pkq[tq][nt][i] = lo | (hi << 16);
        }
    }
    #pragma unroll
    for (int nt = 0; nt < 2; ++nt)
      #pragma unroll
      for (int p = 0; p < 4; ++p) {
        int sl = (((quad & 1)*2 + (p >> 1)) << 4) | l15;
        int a  = __shfl((int)pkq[0][nt][p & 1], sl);
        int c2 = __shfl((int)pkq[1][nt][p & 1], sl);
        qfr[nt].i[p] = (quad >= 2) ? c2 : a;
      }
  }

  // ---- K (own head, all 4 m-tiles) -> A-fragments (same exchange as Q) ----
  {
    f32x4 kacc[2][4] = {};   // [tq][mt]  D[d][m]
    #pragma unroll
    for (int ks = 0; ks < 4; ++ks) {
      short8 hf[4];
      #pragma unroll
      for (int mt = 0; mt < 4; ++mt)
        hf[mt] = *(const short8*)(&hbuf[mt*16 + l15][ks*32 + quad*8]);
      #pragma unroll
      for (int tq = 0; tq < 2; ++tq) {
        short8 wf = *(const short8*)(qkvwb + (128 + h*32 + tq*16 + l15)*128 + ks*32 + quad*8);
        #pragma unroll
        for (int mt = 0; mt < 4; ++mt)
          kacc[tq][mt] = __builtin_amdgcn_mfma_f32_16x16x32_bf16(wf, hf[mt], kacc[tq][mt], 0, 0, 0);
      }
    }
    unsigned pkk[2][4][2];
    #pragma unroll
    for (int tq = 0; tq < 2; ++tq) {
      float bb[4];
      #pragma unroll
      for (int r = 0; r < 4; ++r) bb[r] = qkvb[128 + h*32 + tq*16 + quad*4 + r];
      #pragma unroll
      for (int mt = 0; mt < 4; ++mt)
        #pragma unroll
        for (int i = 0; i < 2; ++i) {
          unsigned lo = (unsigned short)f2bs(kacc[tq][mt][2*i]   + bb[2*i]);
          unsigned hi = (unsigned short)f2bs(kacc[tq][mt][2*i+1] + bb[2*i+1]);
          pkk[tq][mt][i] = lo | (hi << 16);
        }
    }
    #pragma unroll
    for (int mt = 0; mt < 4; ++mt)
      #pragma unroll
      for (int p = 0; p < 4; ++p) {
        int sl = (((quad & 1)*2 + (p >> 1)) << 4) | l15;
        int a  = __shfl((int)pkk[0][mt][p & 1], sl);
        int c2 = __shfl((int)pkk[1][mt][p & 1], sl);
        kfr[mt].i[p] = (quad >= 2) ? c2 : a;
      }
  }

  // ---- V (own head) computed D[m][f] -> A-fragments (same exchange as P) ----
  {
    f32x4 vacc[4][2] = {};   // [mt][dt]  D[m][f]
    #pragma unroll
    for (int ks = 0; ks < 4; ++ks) {
      short8 hf[4];
      #pragma unroll
      for (int mt = 0; mt < 4; ++mt)
        hf[mt] = *(const short8*)(&hbuf[mt*16 + l15][ks*32 + quad*8]);
      #pragma unroll
      for (int dt = 0; dt < 2; ++dt) {
        short8 wf = *(const short8*)(qkvwb + (256 + h*32 + dt*16 + l15)*128 + ks*32 + quad*8);
        #pragma unroll
        for (int mt = 0; mt < 4; ++mt)
          vacc[mt][dt] = __builtin_amdgcn_mfma_f32_16x16x32_bf16(hf[mt], wf, vacc[mt][dt], 0, 0, 0);
      }
    }
    unsigned pkvv[4][2][2];
    #pragma unroll
    for (int dt = 0; dt < 2; ++dt) {
      float bia = qkvb[256 + h*32 + dt*16 + l15];
      #pragma unroll
      for (int mt = 0; mt < 4; ++mt)
        #pragma unroll
        for (int i = 0; i < 2; ++i) {
          int m0 = mt*16 + quad*4;
          float v0 = (m0 + 2*i     < 49) ? (vacc[mt][dt][2*i]   + bia) : 0.f;
          float v1 = (m0 + 2*i + 1 < 49) ? (vacc[mt][dt][2*i+1] + bia) : 0.f;
          unsigned lo = (unsigned short)f2bs(v0);
          unsigned hi = (unsigned short)f2bs(v1);
          pkvv[mt][dt][i] = lo | (hi << 16);
        }
    }
    #pragma unroll
    for (int kt = 0; kt < 2; ++kt)
      #pragma unroll
      for (int dt = 0; dt < 2; ++dt)
        #pragma unroll
        for (int p = 0; p < 4; ++p) {
          int sl = (((quad & 1)*2 + (p >> 1)) << 4) | l15;
          int a  = __shfl((int)pkvv[kt*2    ][dt][p & 1], sl);
          int c2 = __shfl((int)pkvv[kt*2 + 1][dt][p & 1], sl);
          vfr[kt][dt].i[p] = (quad >= 2) ? c2 : a;
        }
  }

  // ---- attention (all-reg; o -> region B) ----
  {
    f32x4 sacc[4][2] = {};   // [mt][nc]: m = mt*16+quad*4+r, n = (half*2+nc)*16+l15
    #pragma unroll
    for (int mt = 0; mt < 4; ++mt)
      #pragma unroll
      for (int nc = 0; nc < 2; ++nc)
        sacc[mt][nc] = __builtin_amdgcn_mfma_f32_16x16x32_bf16(kfr[mt].s, qfr[nc].s, sacc[mt][nc], 0, 0, 0);

    const float* bT = biasT + h*4096;
    #pragma unroll
    for (int mt = 0; mt < 4; ++mt)
      #pragma unroll
      for (int nc = 0; nc < 2; ++nc)
        #pragma unroll
        for (int r = 0; r < 4; ++r)
          sacc[mt][nc][r] += bT[(mt*16 + quad*4 + r)*64 + (half*2 + nc)*16 + l15];

    unsigned pk[4][2][2];
    #pragma unroll
    for (int nc = 0; nc < 2; ++nc) {
      float mx = -1e30f;
      #pragma unroll
      for (int mt = 0; mt < 3; ++mt)
        #pragma unroll
        for (int r = 0; r < 4; ++r) mx = fmaxf(mx, sacc[mt][nc][r]);
      mx = fmaxf(mx, (quad == 0) ? sacc[3][nc][0] : -1e30f);   // m=48 only
      mx = fmaxf(mx, __shfl_xor(mx, 16));
      mx = fmaxf(mx, __shfl_xor(mx, 32));
      float sum = 0.f;
      #pragma unroll
      for (int mt = 0; mt < 3; ++mt)
        #pragma unroll
        for (int r = 0; r < 4; ++r) {
          float e = __expf(sacc[mt][nc][r] - mx);
          sacc[mt][nc][r] = e; sum += e;
        }
      {
        float e = (quad == 0) ? __expf(sacc[3][nc][0] - mx) : 0.f;
        sacc[3][nc][0] = e; sacc[3][nc][1] = 0.f; sacc[3][nc][2] = 0.f; sacc[3][nc][3] = 0.f;
        sum += e;
      }
      sum += __shfl_xor(sum, 16);
      sum += __shfl_xor(sum, 32);
      float inv = 1.f / sum;
      #pragma unroll
      for (int mt = 0; mt < 4; ++mt)
        #pragma unroll
        for (int i = 0; i < 2; ++i) {
          unsigned lo = (unsigned short)f2bs(sacc[mt][nc][2*i]   * inv);
          unsigned hi = (unsigned short)f2bs(sacc[mt][nc][2*i+1] * inv);
          pk[mt][nc][i] = lo | (hi << 16);
        }
    }
    Frag pfr[2][2];
    #pragma unroll
    for (int kt = 0; kt < 2; ++kt)
      #pragma unroll
      for (int nc = 0; nc < 2; ++nc)
        #pragma unroll
        for (int p = 0; p < 4; ++p) {
          int sl = (((quad & 1)*2 + (p >> 1)) << 4) | l15;
          int a  = __shfl((int)pk[kt*2    ][nc][p & 1], sl);
          int c2 = __shfl((int)pk[kt*2 + 1][nc][p & 1], sl);
          pfr[kt][nc].i[p] = (quad >= 2) ? c2 : a;
        }

    f32x4 oacc[2][2] = {};
    #pragma unroll
    for (int kt = 0; kt < 2; ++kt)
      #pragma unroll
      for (int dt = 0; dt < 2; ++dt)
        #pragma unroll
        for (int nc = 0; nc < 2; ++nc)
          oacc[dt][nc] = __builtin_amdgcn_mfma_f32_16x16x32_bf16(vfr[kt][dt].s, pfr[kt][nc].s, oacc[dt][nc], 0, 0, 0);
    #pragma unroll
    for (int dt = 0; dt < 2; ++dt)
      #pragma unroll
      for (int nc = 0; nc < 2; ++nc) {
        int n = (half*2 + nc)*16 + l15;
        if (n < 49) {
          short4v pkv;
          #pragma unroll
          for (int r = 0; r < 4; ++r) pkv[r] = f2bs(oacc[dt][nc][r]);
          *(short4v*)(oB + n*136 + h*32 + dt*16 + quad*4) = pkv;
        }
      }
  }
  __syncthreads();   // B2: o ready; hbuf h dead

  // ---- phase 4: proj + shortcut -> x2 regs + x2b bf16 + LN2 partials ----
  f32x4 x2v[4];   // [mt]: m = mt*16+quad*4+r, f = wave*16+l15
  {
    const int n = wave * 16 + l15;
    float xres[4][4];
    #pragma unroll
    for (int mt = 0; mt < 4; ++mt) {
      #pragma unroll
      for (int r = 0; r < 4; ++r) {
        int m = mt*16 + quad*4 + r;
        float v = 0.f;
        if (m < 49) {
          int rr = m / 7, cc = m - rr * 7;
          int si = wi*7 + rr + 3; if (si >= 56) si -= 56;
          int sj = wj*7 + cc + 3; if (sj >= 56) sj -= 56;
          v = x[(b*3136 + si*56 + sj) * 128 + n];
        }
        xres[mt][r] = v;
      }
    }
    f32x4 acc[4] = {};
    #pragma unroll
    for (int ks = 0; ks < 4; ++ks) {
      short8 af[4];
      #pragma unroll
      for (int mt = 0; mt < 4; ++mt)
        af[mt] = *(const short8*)(oB + (mt*16 + l15)*136 + ks*32 + quad*8);
      short8 bfr = *(const short8*)(projwb + n*128 + ks*32 + quad*8);
      #pragma unroll
      for (int mt = 0; mt < 4; ++mt)
        acc[mt] = __builtin_amdgcn_mfma_f32_16x16x32_bf16(af[mt], bfr, acc[mt], 0, 0, 0);
    }
    float pbv = projb[n];
    #pragma unroll
    for (int mt = 0; mt < 4; ++mt) {
      #pragma unroll
      for (int r = 0; r < 4; ++r) {
        int m = mt*16 + quad*4 + r;
        float v = 0.f;
        if (m < 49) v = acc[mt][r] + pbv + xres[mt][r];
        x2v[mt][r] = v;
        x2b[m*136 + n] = __float2bfloat16(v);
      }
    }
    // LN2 partial stats: 16-lane reduce over this wave's 16 features
    #pragma unroll
    for (int mt = 0; mt < 4; ++mt) {
      #pragma unroll
      for (int r = 0; r < 4; ++r) {
        float s = x2v[mt][r], q = s * s;
        #pragma unroll
        for (int off = 1; off < 16; off <<= 1) {
          s += __shfl_xor(s, off);
          q += __shfl_xor(q, off);
        }
        if (l15 == 0) {
          int m = mt*16 + quad*4 + r;
          pt[m][wave][0] = s; pt[m][wave][1] = q;
        }
      }
    }
  }
  __syncthreads();   // B3: x2b + partials ready; oB dead

  // ---- phase 5: LN2 (exact fp32 stats from partials) -> hbuf bf16 ----
  {
    float g0 = n2g[lane], g1 = n2g[lane+64], e0 = n2b[lane], e1 = n2b[lane+64];
    for (int n = wave; n < 49; n += 8) {
      float s = 0.f, q = 0.f;
      #pragma unroll
      for (int w = 0; w < 8; ++w) { s += pt[n][w][0]; q += pt[n][w][1]; }
      float mean = s * 0.0078125f;
      float var  = q * 0.0078125f - mean*mean;
      float rstd = rsqrtf(var + 1e-5f);
      float v0 = bs2f(x2b[n*136 + lane]), v1 = bs2f(x2b[n*136 + lane + 64]);
      hbuf[n][lane]    = __float2bfloat16((v0-mean)*rstd*g0 + e0);
      hbuf[n][lane+64] = __float2bfloat16((v1-mean)*rstd*g1 + e1);
    }
    __hip_bfloat16 z = __float2bfloat16(0.f);
    for (int n = 49 + wave; n < 64; n += 8) {   // zero pad rows for GEMM1
      hbuf[n][lane] = z; hbuf[n][lane+64] = z;
    }
  }
  __syncthreads();   // B4: ln ready; x2b dead -> hidden bufs free

  // ---- phase 6: MLP, hidden in 4 chunks of 128, double-buffered ----
  f32x4 acc2[4] = {};   // [mt]: m = mt*16+quad*4+r, f = wave*16+l15
  const int fb2 = wave * 16;

  auto G1 = [&](int c, __hip_bfloat16* dst) {
    const int jg = c*128 + wave*16;
    f32x4 a1[4] = {};
    #pragma unroll
    for (int ks = 0; ks < 4; ++ks) {
      short8 lf[4];
      #pragma unroll
      for (int mt = 0; mt < 4; ++mt)
        lf[mt] = *(const short8*)(&hbuf[mt*16 + l15][ks*32 + quad*8]);
      short8 wf = *(const short8*)(w1b + (jg + l15)*128 + ks*32 + quad*8);
      #pragma unroll
      for (int mt = 0; mt < 4; ++mt)
        a1[mt] = __builtin_amdgcn_mfma_f32_16x16x32_bf16(wf, lf[mt], a1[mt], 0, 0, 0);  // D[j][m]
    }
    float bb[4];
    #pragma unroll
    for (int r = 0; r < 4; ++r) bb[r] = b1[jg + quad*4 + r];
    #pragma unroll
    for (int mt = 0; mt < 4; ++mt) {
      int m = mt*16 + l15;
      short4v pkv;
      #pragma unroll
      for (int r = 0; r < 4; ++r) pkv[r] = f2bs(gelu_f(a1[mt][r] + bb[r]));
      *(short4v*)(dst + m*136 + wave*16 + quad*4) = pkv;
    }
  };
  auto G2 = [&](int c, const __hip_bfloat16* src) {
    #pragma unroll
    for (int ks = 0; ks < 4; ++ks) {
      short8 af[4];
      #pragma unroll
      for (int mt = 0; mt < 4; ++mt)
        af[mt] = *(const short8*)(src + (mt*16 + l15)*136 + ks*32 + quad*8);
      short8 wf = *(const short8*)(w2b + (fb2 + l15)*512 + c*128 + ks*32 + quad*8);
      #pragma unroll
      for (int mt = 0; mt < 4; ++mt)
        acc2[mt] = __builtin_amdgcn_mfma_f32_16x16x32_bf16(af[mt], wf, acc2[mt], 0, 0, 0);
    }
  };

  G1(0, hbA);
  __syncthreads();            // B5
  G1(1, hbB); G2(0, hbA);
  __syncthreads();            // B6
  G1(2, hbA); G2(1, hbB);
  __syncthreads();            // B7
  G1(3, hbB); G2(2, hbA);
  __syncthreads();            // B8
  G2(3, hbB);

  // ---- epilogue: bias + register residual, scatter (roll +3) ----
  {
    const int f = fb2 + l15;
    const float bb = b2[f];
    #pragma unroll
    for (int mt = 0; mt < 4; ++mt) {
      #pragma unroll
      for (int r = 0; r < 4; ++r) {
        int m = mt*16 + quad*4 + r;
        if (m < 49) {
          int rr = m / 7, cc = m - rr * 7;
          int si = wi*7 + rr + 3; if (si >= 56) si -= 56;
          int sj = wj*7 + cc + 3; if (sj >= 56) sj -= 56;
          int o = (b*3136 + si*56 + sj) * 128 + f;
          out[o] = acc2[mt][r] + bb + x2v[mt][r];
        }
      }
    }
  }
}

extern "C" void kernel_launch(void* const* d_in, const int* in_sizes, int n_in,
                              void* d_out, int out_size, void* d_ws, size_t ws_size,
                              hipStream_t stream) {
  const float* x     = (const float*)d_in[0];
  const float* n1g   = (const float*)d_in[3];
  const float* n1b   = (const float*)d_in[4];
  const float* qkvw  = (const float*)d_in[5];
  const float* qkvb  = (const float*)d_in[6];
  const float* tab   = (const float*)d_in[7];
  const int*   ridx  = (const int*)d_in[8];
  const float* projw = (const float*)d_in[9];
  const float* projb = (const float*)d_in[10];
  const float* n2g   = (const float*)d_in[11];
  const float* n2b   = (const float*)d_in[12];
  const float* w1    = (const float*)d_in[13];
  const float* b1    = (const float*)d_in[14];
  const float* w2    = (const float*)d_in[15];
  const float* b2    = (const float*)d_in[16];
  float* outp = (float*)d_out;

  __hip_bfloat16* wsb = (__hip_bfloat16*)d_ws;
  float* biasT = (float*)((char*)d_ws + BIAS_BYTE_OFF);

  hipLaunchKernelGGL(conv_kernel, dim3(832), dim3(256), 0, stream,
                     qkvw, projw, w1, w2, tab, ridx, wsb, biasT);
  hipLaunchKernelGGL(fused_kernel, dim3(NWIN), dim3(512), 0, stream,
                     x, n1g, n1b, wsb + QKVW_OFF, qkvb, biasT, wsb + PROJW_OFF, projb,
                     n2g, n2b, wsb + W1_OFF, b1, wsb + W2_OFF, b2, outp);
}

// Round 14
// 255.995 us; speedup vs baseline: 1.2874x; 1.2874x over previous
//
#include <hip/hip_runtime.h>
#include <hip/hip_bf16.h>

// Swin block, B=32 H=W=56 C=128, ws=7 (N=49), nh=4 (hd=32), shift=3, hid=512.
// fp32 in/out. All GEMMs AND attention (QK^T, AV) via mfma_f32_16x16x32_bf16.
// roll(-3) gather == roll(+3) scatter target -> fully fused windows.
// R19: FINAL = resubmission of R10, the session's best (257.35us total,
//     fused 163.9us). Rationale: R18 revealed the occupancy cap is the
//     unified VGPR+AGPR file (64 arch + ~64 acc = 128/wave -> 4 waves/SIMD
//     = 16 waves/CU, independent of LDS). At that fixed residency, three
//     structurally different kernels (R10/R12/R16) all measure 163.5-167.7us
//     fused -- the barrier-chain latency floor of this decomposition.
//     R10 = R9 + systematic weight-fragment prefetch (qkv wfrags under LN1,
//     proj wfrags + residual x rows at p3 end, w1-c0 before p5-end barrier,
//     w2-cN after each GEMM1 epilogue; p6 manually unrolled).

#define NWIN 2048

typedef short short8  __attribute__((ext_vector_type(8)));
typedef short short4v __attribute__((ext_vector_type(4)));
typedef float f32x4   __attribute__((ext_vector_type(4)));

#define QKVW_OFF  0        // 384*128 bf16
#define PROJW_OFF 49152    // 128*128
#define W1_OFF    65536    // 512*128
#define W2_OFF    131072   // 128*512
#define BIAS_BYTE_OFF 393216  // biasT[4][64][64] fp32 (padded, 0 outside 49x49)

__device__ __forceinline__ short f2bs(float v) {
  __hip_bfloat16 h = __float2bfloat16(v);
  union { __hip_bfloat16 h; short s; } u; u.h = h; return u.s;
}
__device__ __forceinline__ float gelu_f(float v) {
  float u = v * (0.7978845608028654f + 0.03567740814f * v * v);
  return v * __builtin_amdgcn_rcpf(1.f + __expf(-2.f * u));
}

// ---------------- pre-pass: weights -> bf16, padded bias^T gather ----------------
__global__ __launch_bounds__(256) void conv_kernel(
    const float* __restrict__ qkvw, const float* __restrict__ projw,
    const float* __restrict__ w1,   const float* __restrict__ w2,
    const float* __restrict__ tab,  const int* __restrict__ ridx,
    __hip_bfloat16* __restrict__ wsb, float* __restrict__ biasT)
{
  int idx = blockIdx.x * 256 + threadIdx.x;
  if (idx < 49152)       wsb[QKVW_OFF + idx]          = __float2bfloat16(qkvw[idx]);
  else if (idx < 65536)  wsb[PROJW_OFF + idx - 49152] = __float2bfloat16(projw[idx - 49152]);
  else if (idx < 131072) wsb[W1_OFF + idx - 65536]    = __float2bfloat16(w1[idx - 65536]);
  else if (idx < 196608) wsb[W2_OFF + idx - 131072]   = __float2bfloat16(w2[idx - 131072]);
  else if (idx < 212992) {
    int i = idx - 196608;
    int h = i >> 12, m = (i >> 6) & 63, n = i & 63;   // biasT[h][m=key][n=query]
    biasT[i] = (m < 49 && n < 49) ? tab[ridx[n*49 + m]*4 + h] : 0.f;
  }
}

// ------- fused: LN1 + window attn + proj + shortcut + LN2 + MLP + residual -------
__global__ __launch_bounds__(512, 4) void fused_kernel(
    const float* __restrict__ x,
    const float* __restrict__ n1g, const float* __restrict__ n1b,
    const __hip_bfloat16* __restrict__ qkvwb, const float* __restrict__ qkvb,
    const float* __restrict__ biasT,
    const __hip_bfloat16* __restrict__ projwb, const float* __restrict__ projb,
    const float* __restrict__ n2g, const float* __restrict__ n2b,
    const __hip_bfloat16* __restrict__ w1b, const float* __restrict__ b1,
    const __hip_bfloat16* __restrict__ w2b, const float* __restrict__ b2,
    float* __restrict__ out)
{
  __shared__ alignas(16) __hip_bfloat16 hbuf[64][136];   // 17408 B: h / o / ln2
  __shared__ alignas(16) char regA[40960];               // qk | x2s fp32 | hidden
  __shared__ alignas(16) __hip_bfloat16 vT[4][32][72];   // 18432 B
  __hip_bfloat16* const qkb = (__hip_bfloat16*)regA;     // qk[4][2][64][40]
  float*          const x2s = (float*)regA;              // [64][132] fp32 (33792 B)
  __hip_bfloat16* const hb  = (__hip_bfloat16*)regA;     // [64][264] (33792 B)

  const int tid = threadIdx.x, wave = tid >> 6, lane = tid & 63;
  const int l15 = lane & 15, quad = lane >> 4;
  const int b = blockIdx.x >> 6, wi = (blockIdx.x >> 3) & 7, wj = blockIdx.x & 7;

  // ---- prefetch: QKV weight fragments for phase 2 (hidden under LN1) ----
  short8 wreg[3][4];
  {
    const int t0 = wave * 3;
    #pragma unroll
    for (int ft = 0; ft < 3; ++ft)
      #pragma unroll
      for (int ks = 0; ks < 4; ++ks)
        wreg[ft][ks] = *(const short8*)(qkvwb + ((t0 + ft)*16 + l15)*128 + ks*32 + quad*8);
  }

  // ---- phase 1: LN1 over source rows (roll -3) -> hbuf bf16.
  //      All global loads issued up-front, then independent reduce chains. ----
  {
    float g0 = n1g[lane], g1 = n1g[lane+64], e0 = n1b[lane], e1 = n1b[lane+64];
    float va[7], vb[7];
    #pragma unroll
    for (int i = 0; i < 7; ++i) {
      int n = wave + i*8;
      va[i] = 0.f; vb[i] = 0.f;
      if (n < 49) {
        int r = n / 7, c = n - r * 7;
        int si = wi*7 + r + 3; if (si >= 56) si -= 56;
        int sj = wj*7 + c + 3; if (sj >= 56) sj -= 56;
        const float* xr = x + (b*3136 + si*56 + sj) * 128;
        va[i] = xr[lane]; vb[i] = xr[lane + 64];
      }
    }
    #pragma unroll
    for (int i = 0; i < 7; ++i) {
      int n = wave + i*8;
      if (n < 49) {
        float s = va[i] + vb[i], sq = va[i]*va[i] + vb[i]*vb[i];
        #pragma unroll
        for (int off = 32; off > 0; off >>= 1) {
          s  += __shfl_xor(s,  off);
          sq += __shfl_xor(sq, off);
        }
        float mean = s * 0.0078125f;
        float var  = sq * 0.0078125f - mean*mean;
        float rstd = rsqrtf(var + 1e-5f);
        hbuf[n][lane]    = __float2bfloat16((va[i]-mean)*rstd*g0 + e0);
        hbuf[n][lane+64] = __float2bfloat16((vb[i]-mean)*rstd*g1 + e1);
      }
    }
  }
  __syncthreads();

  // ---- phase 2: QKV GEMM. 24 tiles of 16 features, 3 per wave, all D[f][m].
  //      Tiles 0-7 = Q, 8-15 = K (vector writes to qk), 16-23 = V (scalar
  //      transpose writes to vT). Weights from prefetched wreg. ----
  {
    const int t0 = wave * 3;
    f32x4 acc[3][4] = {};                 // [ft][mt]  D[f][m]
    #pragma unroll
    for (int ks = 0; ks < 4; ++ks) {
      short8 hf[4];
      #pragma unroll
      for (int mt = 0; mt < 4; ++mt)
        hf[mt] = *(const short8*)(&hbuf[mt*16 + l15][ks*32 + quad*8]);
      #pragma unroll
      for (int ft = 0; ft < 3; ++ft) {
        #pragma unroll
        for (int mt = 0; mt < 4; ++mt)
          acc[ft][mt] = __builtin_amdgcn_mfma_f32_16x16x32_bf16(wreg[ft][ks], hf[mt], acc[ft][mt], 0, 0, 0);
      }
    }
    #pragma unroll
    for (int ft = 0; ft < 3; ++ft) {
      const int t = t0 + ft;
      if (t < 16) {            // Q or K tile
        const int which = t >> 3;
        const int fo = (t & 7) * 16 + quad * 4;    // within-which feature
        const int hh = fo >> 5, d0 = fo & 31;
        const float qs = (t < 8) ? 0.17677669529663687f : 1.0f;
        float bb[4];
        #pragma unroll
        for (int r = 0; r < 4; ++r) bb[r] = qkvb[which*128 + fo + r];
        #pragma unroll
        for (int mt = 0; mt < 4; ++mt) {
          int m = mt*16 + l15;
          if (m < 49) {
            short4v pk;
            #pragma unroll
            for (int r = 0; r < 4; ++r) pk[r] = f2bs((acc[ft][mt][r] + bb[r]) * qs);
            *(short4v*)(qkb + ((hh*2 + which)*64 + m)*40 + d0) = pk;
          }
        }
      } else {                 // V tile: transpose-write into vT[h][d][m]
        const int nf = (t - 16) * 16 + quad * 4;   // V feature 0..127
        const int hh = nf >> 5, d0 = nf & 31;
        float bb[4];
        #pragma unroll
        for (int r = 0; r < 4; ++r) bb[r] = qkvb[256 + nf + r];
        #pragma unroll
        for (int mt = 0; mt < 4; ++mt) {
          int m = mt*16 + l15;
          #pragma unroll
          for (int r = 0; r < 4; ++r) {
            float v = (m < 49) ? (acc[ft][mt][r] + bb[r]) : 0.f;
            vT[hh][d0 + r][m] = __float2bfloat16(v);
          }
        }
      }
    }
  }
  __syncthreads();

  // ---- phase 3: attention, 2 waves per head (query-half split) ----
  short8 pw[4];        // proj weight frags (prefetched at p3 end)
  float xres[4][4];    // residual x rows (prefetched at p3 end)
  {
    const int h = wave >> 1, half = wave & 1;
    __hip_bfloat16* qbase = qkb + (h*2 + 0)*64*40;
    __hip_bfloat16* kbase = qkb + (h*2 + 1)*64*40;
    short8 kf[4], qf[2];
    #pragma unroll
    for (int mt = 0; mt < 4; ++mt) kf[mt] = *(const short8*)(kbase + (mt*16 + l15)*40 + quad*8);
    #pragma unroll
    for (int nt = 0; nt < 2; ++nt)
      qf[nt] = *(const short8*)(qbase + ((half*2 + nt)*16 + l15)*40 + quad*8);
    // hoisted biasT loads: in flight across the barrier (drain absorbs latency)
    const float* bT = biasT + h*4096;
    float bv[4][2][4];
    #pragma unroll
    for (int mt = 0; mt < 4; ++mt)
      #pragma unroll
      for (int nt = 0; nt < 2; ++nt)
        #pragma unroll
        for (int r = 0; r < 4; ++r)
          bv[mt][nt][r] = bT[(mt*16 + quad*4 + r)*64 + (half*2 + nt)*16 + l15];
    __syncthreads();   // all Q/K frag loads done before P overlays the region

    f32x4 sacc[4][2] = {};   // [mt][nt] : m = mt*16+quad*4+r, n = (half*2+nt)*16+l15
    #pragma unroll
    for (int mt = 0; mt < 4; ++mt)
      #pragma unroll
      for (int nt = 0; nt < 2; ++nt)
        sacc[mt][nt] = __builtin_amdgcn_mfma_f32_16x16x32_bf16(kf[mt], qf[nt], sacc[mt][nt], 0, 0, 0);

    #pragma unroll
    for (int mt = 0; mt < 4; ++mt)
      #pragma unroll
      for (int nt = 0; nt < 2; ++nt)
        #pragma unroll
        for (int r = 0; r < 4; ++r)
          sacc[mt][nt][r] += bv[mt][nt][r];

    __hip_bfloat16* pb = qbase;   // P[n][m], stride 72 (q+k region of this head)
    #pragma unroll
    for (int nt = 0; nt < 2; ++nt) {
      float mx = -1e30f;
      #pragma unroll
      for (int mt = 0; mt < 3; ++mt)
        #pragma unroll
        for (int r = 0; r < 4; ++r) mx = fmaxf(mx, sacc[mt][nt][r]);
      mx = fmaxf(mx, (quad == 0) ? sacc[3][nt][0] : -1e30f);   // m=48 only
      mx = fmaxf(mx, __shfl_xor(mx, 16));
      mx = fmaxf(mx, __shfl_xor(mx, 32));
      float sum = 0.f;
      #pragma unroll
      for (int mt = 0; mt < 3; ++mt)
        #pragma unroll
        for (int r = 0; r < 4; ++r) {
          float e = __expf(sacc[mt][nt][r] - mx);
          sacc[mt][nt][r] = e; sum += e;
        }
      {
        float e = (quad == 0) ? __expf(sacc[3][nt][0] - mx) : 0.f;
        sacc[3][nt][0] = e; sacc[3][nt][1] = 0.f; sacc[3][nt][2] = 0.f; sacc[3][nt][3] = 0.f;
        sum += e;
      }
      sum += __shfl_xor(sum, 16);
      sum += __shfl_xor(sum, 32);
      float inv = 1.f / sum;
      int n = (half*2 + nt)*16 + l15;
      #pragma unroll
      for (int mt = 0; mt < 4; ++mt) {
        short4v pk;
        #pragma unroll
        for (int r = 0; r < 4; ++r) pk[r] = f2bs(sacc[mt][nt][r] * inv);
        *(short4v*)(pb + n*72 + mt*16 + quad*4) = pk;
      }
    }

    // AV: A=V^T rows d, B=P rows n (own half) -> D[d][n]
    f32x4 oacc[2][2] = {};
    #pragma unroll
    for (int kt = 0; kt < 2; ++kt) {
      short8 vf[2], pf[2];
      #pragma unroll
      for (int dt = 0; dt < 2; ++dt)
        vf[dt] = *(const short8*)(&vT[h][dt*16 + l15][kt*32 + quad*8]);
      #pragma unroll
      for (int nc = 0; nc < 2; ++nc)
        pf[nc] = *(const short8*)(pb + ((half*2 + nc)*16 + l15)*72 + kt*32 + quad*8);
      #pragma unroll
      for (int dt = 0; dt < 2; ++dt)
        #pragma unroll
        for (int nc = 0; nc < 2; ++nc)
          oacc[dt][nc] = __builtin_amdgcn_mfma_f32_16x16x32_bf16(vf[dt], pf[nc], oacc[dt][nc], 0, 0, 0);
    }
    #pragma unroll
    for (int dt = 0; dt < 2; ++dt)
      #pragma unroll
      for (int nc = 0; nc < 2; ++nc) {
        int n = (half*2 + nc)*16 + l15;
        if (n < 49) {
          short4v pk;
          #pragma unroll
          for (int r = 0; r < 4; ++r) pk[r] = f2bs(oacc[dt][nc][r]);
          *(short4v*)(&hbuf[n][h*32 + dt*16 + quad*4]) = pk;
        }
      }

    // ---- prefetch for phase 4 (issued before the barrier; drain absorbs) ----
    const int ncol0 = wave * 16, n4 = ncol0 + l15;
    #pragma unroll
    for (int ks = 0; ks < 4; ++ks)
      pw[ks] = *(const short8*)(projwb + n4*128 + ks*32 + quad*8);
    #pragma unroll
    for (int mt = 0; mt < 4; ++mt) {
      #pragma unroll
      for (int r = 0; r < 4; ++r) {
        int m = mt*16 + quad*4 + r;
        float v = 0.f;
        if (m < 49) {
          int rr = m / 7, cc = m - rr * 7;
          int si = wi*7 + rr + 3; if (si >= 56) si -= 56;
          int sj = wj*7 + cc + 3; if (sj >= 56) sj -= 56;
          v = x[(b*3136 + si*56 + sj) * 128 + n4];
        }
        xres[mt][r] = v;
      }
    }
  }
  __syncthreads();

  // ---- phase 4: proj + shortcut -> x2 in REGISTERS (fp32) + fp32 LDS mirror ----
  f32x4 x2v[4];   // [mt]: m = mt*16+quad*4+r, f = wave*16+l15
  {
    const int n = wave * 16 + l15;
    f32x4 acc[4] = {};
    #pragma unroll
    for (int ks = 0; ks < 4; ++ks) {
      short8 af[4];
      #pragma unroll
      for (int mt = 0; mt < 4; ++mt)
        af[mt] = *(const short8*)(&hbuf[mt*16 + l15][ks*32 + quad*8]);
      #pragma unroll
      for (int mt = 0; mt < 4; ++mt)
        acc[mt] = __builtin_amdgcn_mfma_f32_16x16x32_bf16(af[mt], pw[ks], acc[mt], 0, 0, 0);
    }
    float pbv = projb[n];
    #pragma unroll
    for (int mt = 0; mt < 4; ++mt) {
      #pragma unroll
      for (int r = 0; r < 4; ++r) {
        int m = mt*16 + quad*4 + r;
        float v = 0.f;
        if (m < 49) v = acc[mt][r] + pbv + xres[mt][r];
        x2v[mt][r] = v;
        x2s[m*132 + n] = v;     // fp32 mirror for LN2 (overlays dead Q/K/P)
      }
    }
  }
  __syncthreads();

  // ---- phase 5: LN2 from x2s -> hbuf bf16 (hbuf o-tile dead now) ----
  {
    float g0 = n2g[lane], g1 = n2g[lane+64], e0 = n2b[lane], e1 = n2b[lane+64];
    for (int n = wave; n < 49; n += 8) {
      float v0 = x2s[n*132 + lane], v1 = x2s[n*132 + lane + 64];
      float s = v0 + v1, sq = v0*v0 + v1*v1;
      #pragma unroll
      for (int off = 32; off > 0; off >>= 1) {
        s  += __shfl_xor(s,  off);
        sq += __shfl_xor(sq, off);
      }
      float mean = s * 0.0078125f;
      float var  = sq * 0.0078125f - mean*mean;
      float rstd = rsqrtf(var + 1e-5f);
      hbuf[n][lane]    = __float2bfloat16((v0-mean)*rstd*g0 + e0);
      hbuf[n][lane+64] = __float2bfloat16((v1-mean)*rstd*g1 + e1);
    }
    __hip_bfloat16 z = __float2bfloat16(0.f);
    for (int n = 49 + wave; n < 64; n += 8) {   // zero pad rows for GEMM1
      hbuf[n][lane] = z; hbuf[n][lane+64] = z;
    }
  }

  // ---- prefetch w1 chunk-0 fragments (before the p5-end barrier) ----
  short8 w1f0[4][2];
  {
    const int jbl = wave * 32;
    #pragma unroll
    for (int ks = 0; ks < 4; ++ks)
      #pragma unroll
      for (int jt = 0; jt < 2; ++jt)
        w1f0[ks][jt] = *(const short8*)(w1b + (jbl + jt*16 + l15)*128 + ks*32 + quad*8);
  }
  __syncthreads();   // x2s reads done -> region A reusable as hidden buf

  // ---- phase 6: MLP, hidden in 2 chunks of 256; GEMM2 accumulates.
  //      Manually unrolled so w2/w1 fragment prefetches sit before barriers. ----
  f32x4 acc2[4] = {};   // [mt]: m = mt*16+quad*4+r, f = wave*16+l15
  short8 w2f[8];
  const int fb2 = wave * 16;

  // -- GEMM1 chunk 0 (prefetched weights) --
  {
    const int jbl = wave * 32;
    f32x4 acc1[2][4] = {};   // [jt][mt]
    #pragma unroll
    for (int ks = 0; ks < 4; ++ks) {
      short8 lf[4];
      #pragma unroll
      for (int mt = 0; mt < 4; ++mt)
        lf[mt] = *(const short8*)(&hbuf[mt*16 + l15][ks*32 + quad*8]);
      #pragma unroll
      for (int jt = 0; jt < 2; ++jt)
        #pragma unroll
        for (int mt = 0; mt < 4; ++mt)
          acc1[jt][mt] = __builtin_amdgcn_mfma_f32_16x16x32_bf16(w1f0[ks][jt], lf[mt], acc1[jt][mt], 0, 0, 0);
    }
    #pragma unroll
    for (int jt = 0; jt < 2; ++jt) {
      int j0l = jbl + jt*16 + quad*4;
      float bb[4];
      #pragma unroll
      for (int r = 0; r < 4; ++r) bb[r] = b1[j0l + r];
      #pragma unroll
      for (int mt = 0; mt < 4; ++mt) {
        int m = mt*16 + l15;
        short4v pk;
        #pragma unroll
        for (int r = 0; r < 4; ++r) pk[r] = f2bs(gelu_f(acc1[jt][mt][r] + bb[r]));
        *(short4v*)(hb + m*264 + j0l) = pk;
      }
    }
  }
  // prefetch w2 chunk-0 fragments (hidden by the hb-ready barrier drain)
  #pragma unroll
  for (int ks = 0; ks < 8; ++ks)
    w2f[ks] = *(const short8*)(w2b + (fb2 + l15)*512 + ks*32 + quad*8);
  __syncthreads();   // hb chunk 0 ready

  // -- GEMM2 partial, chunk 0 --
  #pragma unroll
  for (int ks = 0; ks < 8; ++ks) {
    short8 af[4];
    #pragma unroll
    for (int mt = 0; mt < 4; ++mt)
      af[mt] = *(const short8*)(hb + (mt*16 + l15)*264 + ks*32 + quad*8);
    #pragma unroll
    for (int mt = 0; mt < 4; ++mt)
      acc2[mt] = __builtin_amdgcn_mfma_f32_16x16x32_bf16(af[mt], w2f[ks], acc2[mt], 0, 0, 0);
  }
  __syncthreads();   // hb chunk 0 consumed, safe to overwrite

  // -- GEMM1 chunk 1 (weights loaded in-loop; VGPR pressure headroom) --
  {
    const int jbl = wave * 32;
    f32x4 acc1[2][4] = {};
    #pragma unroll
    for (int ks = 0; ks < 4; ++ks) {
      short8 lf[4];
      #pragma unroll
      for (int mt = 0; mt < 4; ++mt)
        lf[mt] = *(const short8*)(&hbuf[mt*16 + l15][ks*32 + quad*8]);
      #pragma unroll
      for (int jt = 0; jt < 2; ++jt) {
        short8 wf = *(const short8*)(w1b + (256 + jbl + jt*16 + l15)*128 + ks*32 + quad*8);
        #pragma unroll
        for (int mt = 0; mt < 4; ++mt)
          acc1[jt][mt] = __builtin_amdgcn_mfma_f32_16x16x32_bf16(wf, lf[mt], acc1[jt][mt], 0, 0, 0);
      }
    }
    #pragma unroll
    for (int jt = 0; jt < 2; ++jt) {
      int j0l = jbl + jt*16 + quad*4;
      float bb[4];
      #pragma unroll
      for (int r = 0; r < 4; ++r) bb[r] = b1[256 + j0l + r];
      #pragma unroll
      for (int mt = 0; mt < 4; ++mt) {
        int m = mt*16 + l15;
        short4v pk;
        #pragma unroll
        for (int r = 0; r < 4; ++r) pk[r] = f2bs(gelu_f(acc1[jt][mt][r] + bb[r]));
        *(short4v*)(hb + m*264 + j0l) = pk;
      }
    }
  }
  // prefetch w2 chunk-1 fragments (hidden by the hb-ready barrier drain)
  #pragma unroll
  for (int ks = 0; ks < 8; ++ks)
    w2f[ks] = *(const short8*)(w2b + (fb2 + l15)*512 + 256 + ks*32 + quad*8);
  __syncthreads();   // hb chunk 1 ready

  // -- GEMM2 partial, chunk 1 --
  #pragma unroll
  for (int ks = 0; ks < 8; ++ks) {
    short8 af[4];
    #pragma unroll
    for (int mt = 0; mt < 4; ++mt)
      af[mt] = *(const short8*)(hb + (mt*16 + l15)*264 + ks*32 + quad*8);
    #pragma unroll
    for (int mt = 0; mt < 4; ++mt)
      acc2[mt] = __builtin_amdgcn_mfma_f32_16x16x32_bf16(af[mt], w2f[ks], acc2[mt], 0, 0, 0);
  }

  // ---- epilogue: bias + register residual, scatter (roll +3) ----
  {
    const int f = fb2 + l15;
    const float bb = b2[f];
    #pragma unroll
    for (int mt = 0; mt < 4; ++mt) {
      #pragma unroll
      for (int r = 0; r < 4; ++r) {
        int m = mt*16 + quad*4 + r;
        if (m < 49) {
          int rr = m / 7, cc = m - rr * 7;
          int si = wi*7 + rr + 3; if (si >= 56) si -= 56;
          int sj = wj*7 + cc + 3; if (sj >= 56) sj -= 56;
          int o = (b*3136 + si*56 + sj) * 128 + f;
          out[o] = acc2[mt][r] + bb + x2v[mt][r];
        }
      }
    }
  }
}

extern "C" void kernel_launch(void* const* d_in, const int* in_sizes, int n_in,
                              void* d_out, int out_size, void* d_ws, size_t ws_size,
                              hipStream_t stream) {
  const float* x     = (const float*)d_in[0];
  const float* n1g   = (const float*)d_in[3];
  const float* n1b   = (const float*)d_in[4];
  const float* qkvw  = (const float*)d_in[5];
  const float* qkvb  = (const float*)d_in[6];
  const float* tab   = (const float*)d_in[7];
  const int*   ridx  = (const int*)d_in[8];
  const float* projw = (const float*)d_in[9];
  const float* projb = (const float*)d_in[10];
  const float* n2g   = (const float*)d_in[11];
  const float* n2b   = (const float*)d_in[12];
  const float* w1    = (const float*)d_in[13];
  const float* b1    = (const float*)d_in[14];
  const float* w2    = (const float*)d_in[15];
  const float* b2    = (const float*)d_in[16];
  float* outp = (float*)d_out;

  __hip_bfloat16* wsb = (__hip_bfloat16*)d_ws;
  float* biasT = (float*)((char*)d_ws + BIAS_BYTE_OFF);

  hipLaunchKernelGGL(conv_kernel, dim3(832), dim3(256), 0, stream,
                     qkvw, projw, w1, w2, tab, ridx, wsb, biasT);
  hipLaunchKernelGGL(fused_kernel, dim3(NWIN), dim3(512), 0, stream,
                     x, n1g, n1b, wsb + QKVW_OFF, qkvb, biasT, wsb + PROJW_OFF, projb,
                     n2g, n2b, wsb + W1_OFF, b1, wsb + W2_OFF, b2, outp);
}